// Round 17
// baseline (148.523 us; speedup 1.0000x reference)
//
#include <hip/hip_runtime.h>

#define B_   128
#define T_   256
#define C_   384
#define H_   6
#define D_   64
#define M_   128
#define WIN_ 64
#define C3_  1152
#define QKS_ 768   // qk workspace row stride (q cols 0..383, k cols 384..767)

typedef unsigned int   uint;
typedef unsigned short ushort;
typedef __attribute__((ext_vector_type(8))) short bf16x8;
typedef __attribute__((ext_vector_type(4))) float f32x4;

#define AS1 __attribute__((address_space(1)))
#define AS3 __attribute__((address_space(3)))
#define MFMA16(a,b,c) __builtin_amdgcn_mfma_f32_16x16x32_bf16((a),(b),(c),0,0,0)
#define SCHED_FENCE() __builtin_amdgcn_sched_barrier(0)

__device__ __forceinline__ ushort f2bf(float f) {
  union { float f; uint u; } c; c.f = f;
  uint x = c.u;
  return (ushort)((x + 0x7fffu + ((x >> 16) & 1u)) >> 16);  // RNE
}
__device__ __forceinline__ uint cvtpk(float lo, float hi) {
  uint r;
  asm("v_cvt_pk_bf16_f32 %0, %1, %2" : "=v"(r) : "v"(lo), "v"(hi));
  return r;
}
__device__ __forceinline__ void gload_lds16(const ushort* g, ushort* l) {
  __builtin_amdgcn_global_load_lds((const AS1 uint*)g, (AS3 uint*)l, 16, 0, 0);
}

// ---------------------------------------------------------------------------
// Prep (validated R5/R8): x->bf16, memory->bf16, memT[h][d][k], Wq_t, Wp_t.
// ---------------------------------------------------------------------------
#define NX4_  ((B_ * T_ * C_) / 4)   // 3145728
#define NM4_  ((M_ * C_) / 4)        // 12288
#define NMT_  (H_ * 64 * 128)        // 49152
#define NWQ_  (C_ * C3_)             // 442368
#define NWP_  (C_ * C_)              // 147456

__global__ __launch_bounds__(256)
void k_prep(const float* __restrict__ x, const float* __restrict__ memory,
            const float* __restrict__ Wq, const float* __restrict__ Wp,
            ushort* __restrict__ x_bf, ushort* __restrict__ mem_bf,
            ushort* __restrict__ memT, ushort* __restrict__ Wq_t,
            ushort* __restrict__ Wp_t)
{
  int id = blockIdx.x * 256 + threadIdx.x;
  if (id < NX4_) {
    float4 f = ((const float4*)x)[id];
    ushort4 u; u.x = f2bf(f.x); u.y = f2bf(f.y); u.z = f2bf(f.z); u.w = f2bf(f.w);
    *(ushort4*)&x_bf[id * 4] = u;
    return;
  }
  id -= NX4_;
  if (id < NM4_) {
    float4 f = ((const float4*)memory)[id];
    ushort4 u; u.x = f2bf(f.x); u.y = f2bf(f.y); u.z = f2bf(f.z); u.w = f2bf(f.w);
    *(ushort4*)&mem_bf[id * 4] = u;
    return;
  }
  id -= NM4_;
  if (id < NMT_) {                 // memT[(h*64+d)*128 + k] = memory[k][h*64+d]
    int k = id & 127;
    int hd = id >> 7;
    int h = hd >> 6, d = hd & 63;
    memT[id] = f2bf(memory[(size_t)k * C_ + h * 64 + d]);
    return;
  }
  id -= NMT_;
  if (id < NWQ_) {                 // Wq_t[n*384 + k] = Wq[k*1152 + n]
    int n = id / C_, k = id % C_;
    Wq_t[id] = f2bf(Wq[(size_t)k * C3_ + n]);
    return;
  }
  id -= NWQ_;
  if (id < NWP_) {                 // Wp_t[n*384 + k] = Wp[k*384 + n]
    int n = id / C_, k = id % C_;
    Wp_t[id] = f2bf(Wp[(size_t)k * C_ + n]);
  }
}

// ---------------------------------------------------------------------------
// GEMM0 (qkv) — R14/R16 verbatim: 256x128 tile, 512 threads, 3-buffer
// single-barrier K-loop, sched-fence race protection, vmcnt(3) counted.
// Measured 43.2 us (R16, passed).
// ---------------------------------------------------------------------------
__global__ __launch_bounds__(512, 4)
void k_gemm0(const ushort* __restrict__ A, const ushort* __restrict__ Bt,
             const float* __restrict__ bias, ushort* __restrict__ qkw,
             ushort* __restrict__ vTw)
{
  __shared__ __align__(16) ushort smem[36864];   // 72 KB
  constexpr int NT = 9;
  const int wg = blockIdx.x;
  const int X = wg & 7, j = wg >> 3;
  const int bmT = X * 16 + j / NT;               // 128 M-tiles, 16 per XCD
  const int by = j - (j / NT) * NT;
  const int bm = bmT * 256, bn = by * 128;
  const int tid = threadIdx.x;
  const int lane = tid & 63, w = tid >> 6;
  const int wr = w >> 1, wc = w & 1;
  const int g = lane >> 4, l15 = lane & 15;

  f32x4 acc[4][4] = {};

  auto stage = [&](int buf, int k0) {            // 3 gload_lds per thread
    #pragma unroll
    for (int i = 0; i < 2; ++i) {                // A: 1024 slots (256 rows x 32)
      int s = i * 512 + tid;
      int row = s >> 2, cS = s & 3;
      int c = cS ^ ((row >> 1) & 3);
      gload_lds16(A + (size_t)(bm + row) * C_ + k0 + c * 8, &smem[buf * 8192 + s * 8]);
    }
    {                                            // B: 512 slots (128 rows x 32)
      int s = tid;
      int row = s >> 2, cS = s & 3;
      int c = cS ^ ((row >> 1) & 3);
      gload_lds16(Bt + (size_t)(bn + row) * C_ + k0 + c * 8, &smem[24576 + buf * 4096 + s * 8]);
    }
  };

  stage(0, 0);
  stage(1, 32);
  SCHED_FENCE();
  asm volatile("s_waitcnt vmcnt(3)" ::: "memory");   // stage(0) retired
  __builtin_amdgcn_s_barrier();
  SCHED_FENCE();

  #pragma unroll
  for (int t = 0; t < 12; ++t) {
    const int cur = t % 3;
    if (t < 10) stage((t + 2) % 3, (t + 2) * 32);

    bf16x8 af[4], bfr[4];
    #pragma unroll
    for (int m = 0; m < 4; ++m) {
      int row = wr * 64 + m * 16 + l15;          // 0..255
      int c = g ^ ((row >> 1) & 3);
      af[m] = *(const bf16x8*)&smem[cur * 8192 + row * 32 + c * 8];
    }
    #pragma unroll
    for (int n = 0; n < 4; ++n) {
      int row = wc * 64 + n * 16 + l15;          // 0..127
      int c = g ^ ((row >> 1) & 3);
      bfr[n] = *(const bf16x8*)&smem[24576 + cur * 4096 + row * 32 + c * 8];
    }
    #pragma unroll
    for (int m = 0; m < 4; ++m)
      #pragma unroll
      for (int n = 0; n < 4; ++n)
        acc[m][n] = MFMA16(af[m], bfr[n], acc[m][n]);

    if (t < 11) {
      SCHED_FENCE();                              // pin reads/MFMA above barrier
      if (t < 10) asm volatile("s_waitcnt vmcnt(3)" ::: "memory");  // stage(t+1) retired
      else        asm volatile("s_waitcnt vmcnt(0)" ::: "memory");  // last buf ready
      __builtin_amdgcn_s_barrier();
      SCHED_FENCE();                              // pin next stage/reads below
    }
  }

  if (by < 6) {
    // qk: LDS-staged swizzled store, 256x128 tile, full-line writes
    __syncthreads();                      // smem reuse safe (full fence)
    #pragma unroll
    for (int m = 0; m < 4; ++m)
      #pragma unroll
      for (int n = 0; n < 4; ++n) {
        int colL = wc * 64 + n * 16 + l15;
        float bv = bias[bn + colL];
        #pragma unroll
        for (int r = 0; r < 4; ++r) {
          int rowL = wr * 64 + m * 16 + g * 4 + r;     // 0..255
          smem[rowL * 128 + (colL ^ ((rowL & 7) << 3))] = f2bf(acc[m][n][r] + bv);
        }
      }
    __syncthreads();
    #pragma unroll
    for (int i = 0; i < 8; ++i) {
      int rowL = (tid >> 2) + (i >> 2) * 128;   // 0..255
      int slot = (i & 3) * 4 + (tid & 3);       // 0..15
      int c = slot * 8;
      bf16x8 vv = *(const bf16x8*)&smem[rowL * 128 + (c ^ ((rowL & 7) << 3))];
      *(bf16x8*)(qkw + (size_t)(bm + rowL) * QKS_ + bn + c) = vv;
    }
  } else {
    // v: LDS transpose staging (stride 272 = 17x16B -> aligned), full-row stores
    ushort (*CsT)[272] = (ushort(*)[272])smem;  // 128 x 272 = 34816 <= 36864
    __syncthreads();                      // smem reuse safe (full fence)
    #pragma unroll
    for (int m = 0; m < 4; ++m)
      #pragma unroll
      for (int n = 0; n < 4; ++n) {
        int colL = wc * 64 + n * 16 + l15;
        float bv = bias[bn + colL];
        int row0 = wr * 64 + m * 16 + g * 4;    // 0..255 (keys)
        uint lo = (uint)f2bf(acc[m][n][0] + bv) | ((uint)f2bf(acc[m][n][1] + bv) << 16);
        uint hi = (uint)f2bf(acc[m][n][2] + bv) | ((uint)f2bf(acc[m][n][3] + bv) << 16);
        uint2 uu; uu.x = lo; uu.y = hi;
        *(uint2*)&CsT[colL][row0] = uu;
      }
    __syncthreads();
    #pragma unroll
    for (int i = 0; i < 8; ++i) {
      int s = i * 512 + tid;                    // 4096 slots
      int colL = s >> 5;                        // 0..127
      int kc = s & 31;                          // 16B chunk along 256 keys
      int ch = (bn - 768) + colL;
      int hh = ch >> 6, dd = ch & 63;
      bf16x8 vv = *(const bf16x8*)&CsT[colL][kc * 8];
      *(bf16x8*)(vTw + ((size_t)(bmT * H_ + hh) * 64 + dd) * 256 + kc * 8) = vv;
    }
  }
}

// ---------------------------------------------------------------------------
// GEMM1 (proj) — R13/R16 verbatim: 128x128 tile, 256 threads, 3-buffer
// single-barrier K-loop with fences, vmcnt(4) counted, direct f32 stores.
// ---------------------------------------------------------------------------
__global__ __launch_bounds__(256, 3)
void k_gemm1(const ushort* __restrict__ A, const ushort* __restrict__ Bt,
             const float* __restrict__ bias, float* __restrict__ outf)
{
  __shared__ __align__(16) ushort smem[24576];   // A: 3x4096 | B: 3x4096
  constexpr int NT = 3;
  const int wg = blockIdx.x;
  const int X = wg & 7, j = wg >> 3;
  const int bmT = X * 32 + j / NT;
  const int by = j - (j / NT) * NT;
  const int bm = bmT * 128, bn = by * 128;
  const int tid = threadIdx.x;
  const int lane = tid & 63, w = tid >> 6;
  const int wr = w >> 1, wc = w & 1;
  const int g = lane >> 4, l15 = lane & 15;

  f32x4 acc[4][4] = {};

  auto stage = [&](int buf, int k0) {           // 4 gload_lds per thread
    #pragma unroll
    for (int i = 0; i < 2; ++i) {
      int s = i * 256 + tid;
      int row = s >> 2, cS = s & 3;
      int c = cS ^ ((row >> 1) & 3);
      gload_lds16(A  + (size_t)(bm + row) * C_ + k0 + c * 8, &smem[buf * 4096 + s * 8]);
      gload_lds16(Bt + (size_t)(bn + row) * C_ + k0 + c * 8, &smem[12288 + buf * 4096 + s * 8]);
    }
  };

  stage(0, 0);
  stage(1, 32);
  SCHED_FENCE();
  asm volatile("s_waitcnt vmcnt(4)" ::: "memory");
  __builtin_amdgcn_s_barrier();
  SCHED_FENCE();

  #pragma unroll
  for (int t = 0; t < 12; ++t) {
    const int cur = t % 3;
    if (t < 10) stage((t + 2) % 3, (t + 2) * 32);

    bf16x8 af[4], bfr[4];
    #pragma unroll
    for (int m = 0; m < 4; ++m) {
      int row = wr * 64 + m * 16 + l15;
      int c = g ^ ((row >> 1) & 3);
      af[m] = *(const bf16x8*)&smem[cur * 4096 + row * 32 + c * 8];
    }
    #pragma unroll
    for (int n = 0; n < 4; ++n) {
      int row = wc * 64 + n * 16 + l15;
      int c = g ^ ((row >> 1) & 3);
      bfr[n] = *(const bf16x8*)&smem[12288 + cur * 4096 + row * 32 + c * 8];
    }
    #pragma unroll
    for (int m = 0; m < 4; ++m)
      #pragma unroll
      for (int n = 0; n < 4; ++n)
        acc[m][n] = MFMA16(af[m], bfr[n], acc[m][n]);

    if (t < 11) {
      SCHED_FENCE();
      if (t < 10) asm volatile("s_waitcnt vmcnt(4)" ::: "memory");
      else        asm volatile("s_waitcnt vmcnt(0)" ::: "memory");
      __builtin_amdgcn_s_barrier();
      SCHED_FENCE();
    }
  }

  #pragma unroll
  for (int m = 0; m < 4; ++m)
    #pragma unroll
    for (int n = 0; n < 4; ++n) {
      int col = bn + wc * 64 + n * 16 + l15;
      float bv = bias[col];
      #pragma unroll
      for (int r = 0; r < 4; ++r) {
        int row = bm + wr * 64 + m * 16 + g * 4 + r;
        outf[(size_t)row * C_ + col] = acc[m][n][r] + bv;
      }
    }
}

// ---------------------------------------------------------------------------
// Attention — R8/R16 validated dataflow + TWO additions:
//   (1) T14 V-prefetch: chunk ch+1's V fragments issued during chunk ch
//       (after QK), waited at next chunk's PV -> ~400+ cyc latency cover
//       for the global vTw reads (24MB, partially HBM-missing).
//   (2) T5 s_setprio(1) around both MFMA clusters (waves are barrier-free
//       and phase-diverse -> the regime where setprio measured +4-7%).
// ---------------------------------------------------------------------------
__global__ __launch_bounds__(512, 4)
void k_attn(const ushort* __restrict__ qkw, const ushort* __restrict__ vTw,
            const ushort* __restrict__ membf, const ushort* __restrict__ memT,
            const float* __restrict__ gate, ushort* __restrict__ y)
{
  __shared__ ushort Ks[2][384][32];   // mem(0..127)+self(128..383) K, col-XOR swizzled
  __shared__ ushort Pb[8][32 * 32];   // per-wave P tile, sigma-swizzled

  const int b = blockIdx.x, h = blockIdx.y;
  const int tid = threadIdx.x, lane = tid & 63, w = tid >> 6;
  const int g = lane >> 4, l15 = lane & 15;
  const int q0 = w * 32;

  const ushort* qbase = qkw + (size_t)b * T_ * QKS_ + h * 64;
  const ushort* kcols = qbase + C_;                       // self-k columns
  const ushort* vbase = vTw + (size_t)(b * H_ + h) * 64 * 256;
  const ushort* mTb   = memT + (size_t)h * 64 * 128;
  const ushort* mKb   = membf + h * 64;

  // ---- stage Ks: 3072 16B slots over 512 threads ----
  #pragma unroll
  for (int i = 0; i < 6; ++i) {
    int s = i * 512 + tid;
    int kk = s / 1536, r4 = s - kk * 1536;
    int row = r4 >> 2, cS = r4 & 3;
    int c = cS ^ ((row >> 1) & 3);                        // inverse swizzle on source
    const ushort* src = (row < M_)
        ? mKb + (size_t)row * C_ + kk * 32 + c * 8
        : kcols + (size_t)(row - M_) * QKS_ + kk * 32 + c * 8;
    gload_lds16(src, &Ks[0][0][0] + s * 8);
  }

  // ---- Q fragments ----
  bf16x8 qf[2][2];
  #pragma unroll
  for (int m = 0; m < 2; ++m)
    #pragma unroll
    for (int kk = 0; kk < 2; ++kk)
      qf[m][kk] = *(const bf16x8*)(qbase + (size_t)(q0 + m * 16 + l15) * QKS_ + kk * 32 + g * 8);

  __syncthreads();   // drains global_load_lds (full fence)

  f32x4 yacc[2][4] = {};
  float rsum[2][4] = {};
  ushort* P = &Pb[w][0];

  const int c0 = (q0 >= WIN_) ? ((q0 - WIN_) >> 5) : 0;
  const int nch_self = (q0 >> 5) - c0 + 1;
  const int nch = 4 + nch_self;
  const int ss = M_ + c0 * 32;

  bf16x8 vb_cur[4], vb_nxt[4];
  auto loadV = [&](int ch, bf16x8 (&vb)[4]) {
    const bool im = (ch < 4);
    const int r0v = im ? ch * 32 : ss + (ch - 4) * 32;
    const ushort* vsrc = im ? mTb : vbase;
    const int vld = im ? 128 : 256;
    const int keyoff = im ? r0v : (r0v - M_);
    #pragma unroll
    for (int n = 0; n < 4; ++n)
      vb[n] = *(const bf16x8*)(vsrc + (size_t)(n * 16 + l15) * vld + keyoff + g * 8);
  };

  loadV(0, vb_cur);

  for (int ch = 0; ch < nch; ++ch) {
    const bool is_mem = (ch < 4);
    const int r0 = is_mem ? ch * 32 : ss + (ch - 4) * 32;

    // ---- QK^T: S[32 q][32 keys] ----
    f32x4 s_[2][2];
    #pragma unroll
    for (int m = 0; m < 2; ++m)
      #pragma unroll
      for (int n = 0; n < 2; ++n)
        s_[m][n] = (f32x4){0.f, 0.f, 0.f, 0.f};
    __builtin_amdgcn_s_setprio(1);
    #pragma unroll
    for (int n = 0; n < 2; ++n) {
      int R = r0 + n * 16 + l15;
      int c = g ^ ((R >> 1) & 3);
      #pragma unroll
      for (int kk = 0; kk < 2; ++kk) {
        bf16x8 kf = *(const bf16x8*)&Ks[kk][R][c * 8];
        #pragma unroll
        for (int m = 0; m < 2; ++m)
          s_[m][n] = MFMA16(qf[m][kk], kf, s_[m][n]);
      }
    }
    __builtin_amdgcn_s_setprio(0);

    // ---- prefetch next chunk's V (waited at next iteration's PV) ----
    if (ch + 1 < nch) loadV(ch + 1, vb_nxt);

    // ---- mask + exp + P write ----
    #pragma unroll
    for (int m = 0; m < 2; ++m)
      #pragma unroll
      for (int n = 0; n < 2; ++n) {
        int key_row = r0 + n * 16 + l15;
        int jj = key_row - M_;
        int kc = n * 16 + l15;
        float p[4];
        #pragma unroll
        for (int r = 0; r < 4; ++r) {
          int qi = q0 + m * 16 + g * 4 + r;
          bool ok = is_mem || ((jj <= qi) && (qi - jj <= WIN_));
          float e = ok ? exp2f(s_[m][n][r] * 0.18033688011112042f) : 0.f;
          rsum[m][r] += e;
          p[r] = e;
        }
        uint u01 = cvtpk(p[0], p[1]);
        uint u23 = cvtpk(p[2], p[3]);
        #pragma unroll
        for (int r = 0; r < 4; ++r) {
          int ql = m * 16 + g * 4 + r;
          int sig = ((ql >> 1) ^ (ql >> 2)) & 3;
          uint u = (r < 2) ? u01 : u23;
          ushort val = (r & 1) ? (ushort)(u >> 16) : (ushort)(u & 0xffffu);
          P[ql * 32 + (kc ^ (sig << 3))] = val;
        }
      }

    // ---- PV: yacc += P[32x32] * V[32 keys x 64 d] ----
    bf16x8 pa[2];
    #pragma unroll
    for (int m = 0; m < 2; ++m) {
      int row = m * 16 + l15;
      int sig = ((row >> 1) ^ (row >> 2)) & 3;
      pa[m] = *(const bf16x8*)&P[row * 32 + ((g ^ sig) << 3)];
    }
    __builtin_amdgcn_s_setprio(1);
    #pragma unroll
    for (int n = 0; n < 4; ++n)
      #pragma unroll
      for (int m = 0; m < 2; ++m)
        yacc[m][n] = MFMA16(pa[m], vb_cur[n], yacc[m][n]);
    __builtin_amdgcn_s_setprio(0);

    // rotate prefetched V into place
    #pragma unroll
    for (int n = 0; n < 4; ++n) vb_cur[n] = vb_nxt[n];
  }

  // ---- row-sum reduce across the 16 lanes sharing each q row ----
  float inv[2][4];
  #pragma unroll
  for (int m = 0; m < 2; ++m)
    #pragma unroll
    for (int r = 0; r < 4; ++r) {
      float v = rsum[m][r];
      v += __shfl_xor(v, 1); v += __shfl_xor(v, 2);
      v += __shfl_xor(v, 4); v += __shfl_xor(v, 8);
      inv[m][r] = 1.f / v;
    }

  // ---- epilogue: y = (P V / l) * gate, bf16 ----
  #pragma unroll
  for (int m = 0; m < 2; ++m)
    #pragma unroll
    for (int n = 0; n < 4; ++n) {
      int dd = n * 16 + l15;
      float gv = gate[h * 64 + dd];
      #pragma unroll
      for (int r = 0; r < 4; ++r) {
        int qi = q0 + m * 16 + g * 4 + r;
        y[(size_t)(b * T_ + qi) * C_ + h * 64 + dd] = f2bf(yacc[m][n][r] * inv[m][r] * gv);
      }
    }
}

// ---------------------------------------------------------------------------
extern "C" void kernel_launch(void* const* d_in, const int* in_sizes, int n_in,
                              void* d_out, int out_size, void* d_ws, size_t ws_size,
                              hipStream_t stream) {
  const float* x      = (const float*)d_in[0];
  const float* memory = (const float*)d_in[1];
  const float* W_qkv  = (const float*)d_in[2];
  const float* b_qkv  = (const float*)d_in[3];
  const float* W_proj = (const float*)d_in[4];
  const float* b_proj = (const float*)d_in[5];
  const float* gate   = (const float*)d_in[6];
  float* out = (float*)d_out;

  ushort* p = (ushort*)d_ws;
  ushort* Wq_t  = p;  p += (size_t)C_ * C3_;          //   442368
  ushort* Wp_t  = p;  p += (size_t)C_ * C_;           //   147456
  ushort* membf = p;  p += (size_t)M_ * C_;           //    49152
  ushort* memT  = p;  p += (size_t)NMT_;              //    49152
  ushort* qkw   = p;  p += (size_t)B_ * T_ * QKS_;    // 25165824
  ushort* vTw   = p;  p += (size_t)B_ * T_ * C_;      // 12582912
  ushort* xybf  = p;  p += (size_t)B_ * T_ * C_;      // 12582912 (x_bf, then y)

  dim3 blk(256);

  int prep_items = NX4_ + NM4_ + NMT_ + NWQ_ + NWP_;
  k_prep<<<dim3((prep_items + 255) / 256), blk, 0, stream>>>(
      x, memory, W_qkv, W_proj, xybf, membf, memT, Wq_t, Wp_t);

  k_gemm0<<<dim3(1152), dim3(512), 0, stream>>>(xybf, Wq_t, b_qkv, qkw, vTw);

  k_attn<<<dim3(B_, H_), dim3(512), 0, stream>>>(qkw, vTw, membf, memT, gate, xybf);

  k_gemm1<<<dim3(768), blk, 0, stream>>>(xybf, Wp_t, b_proj, out);
}

// Round 18
// 109.201 us; speedup vs baseline: 1.3601x; 1.3601x over previous
//
#include <hip/hip_runtime.h>

#define B_   128
#define T_   256
#define C_   384
#define H_   6
#define D_   64
#define M_   128
#define WIN_ 64
#define C3_  1152
#define QKS_ 768   // qk workspace row stride (q cols 0..383, k cols 384..767)

typedef unsigned int   uint;
typedef unsigned short ushort;
typedef __attribute__((ext_vector_type(8))) short bf16x8;
typedef __attribute__((ext_vector_type(4))) float f32x4;

#define AS1 __attribute__((address_space(1)))
#define AS3 __attribute__((address_space(3)))
#define MFMA16(a,b,c) __builtin_amdgcn_mfma_f32_16x16x32_bf16((a),(b),(c),0,0,0)
#define SCHED_FENCE() __builtin_amdgcn_sched_barrier(0)

__device__ __forceinline__ ushort f2bf(float f) {
  union { float f; uint u; } c; c.f = f;
  uint x = c.u;
  return (ushort)((x + 0x7fffu + ((x >> 16) & 1u)) >> 16);  // RNE
}
__device__ __forceinline__ uint cvtpk(float lo, float hi) {
  uint r;
  asm("v_cvt_pk_bf16_f32 %0, %1, %2" : "=v"(r) : "v"(lo), "v"(hi));
  return r;
}
__device__ __forceinline__ void gload_lds16(const ushort* g, ushort* l) {
  __builtin_amdgcn_global_load_lds((const AS1 uint*)g, (AS3 uint*)l, 16, 0, 0);
}

// ---------------------------------------------------------------------------
// Prep (validated R5/R8): x->bf16, memory->bf16, memT[h][d][k], Wq_t, Wp_t.
// ---------------------------------------------------------------------------
#define NX4_  ((B_ * T_ * C_) / 4)   // 3145728
#define NM4_  ((M_ * C_) / 4)        // 12288
#define NMT_  (H_ * 64 * 128)        // 49152
#define NWQ_  (C_ * C3_)             // 442368
#define NWP_  (C_ * C_)              // 147456

__global__ __launch_bounds__(256)
void k_prep(const float* __restrict__ x, const float* __restrict__ memory,
            const float* __restrict__ Wq, const float* __restrict__ Wp,
            ushort* __restrict__ x_bf, ushort* __restrict__ mem_bf,
            ushort* __restrict__ memT, ushort* __restrict__ Wq_t,
            ushort* __restrict__ Wp_t)
{
  int id = blockIdx.x * 256 + threadIdx.x;
  if (id < NX4_) {
    float4 f = ((const float4*)x)[id];
    ushort4 u; u.x = f2bf(f.x); u.y = f2bf(f.y); u.z = f2bf(f.z); u.w = f2bf(f.w);
    *(ushort4*)&x_bf[id * 4] = u;
    return;
  }
  id -= NX4_;
  if (id < NM4_) {
    float4 f = ((const float4*)memory)[id];
    ushort4 u; u.x = f2bf(f.x); u.y = f2bf(f.y); u.z = f2bf(f.z); u.w = f2bf(f.w);
    *(ushort4*)&mem_bf[id * 4] = u;
    return;
  }
  id -= NM4_;
  if (id < NMT_) {                 // memT[(h*64+d)*128 + k] = memory[k][h*64+d]
    int k = id & 127;
    int hd = id >> 7;
    int h = hd >> 6, d = hd & 63;
    memT[id] = f2bf(memory[(size_t)k * C_ + h * 64 + d]);
    return;
  }
  id -= NMT_;
  if (id < NWQ_) {                 // Wq_t[n*384 + k] = Wq[k*1152 + n]
    int n = id / C_, k = id % C_;
    Wq_t[id] = f2bf(Wq[(size_t)k * C3_ + n]);
    return;
  }
  id -= NWQ_;
  if (id < NWP_) {                 // Wp_t[n*384 + k] = Wp[k*384 + n]
    int n = id / C_, k = id % C_;
    Wp_t[id] = f2bf(Wp[(size_t)k * C_ + n]);
  }
}

// ---------------------------------------------------------------------------
// GEMM0 (qkv) — R14/R16 verbatim: 256x128 tile, 512 threads, 3-buffer
// single-barrier K-loop, sched-fence race protection, vmcnt(3) counted.
// Measured 43.2 us (R16, passed).
// ---------------------------------------------------------------------------
__global__ __launch_bounds__(512, 4)
void k_gemm0(const ushort* __restrict__ A, const ushort* __restrict__ Bt,
             const float* __restrict__ bias, ushort* __restrict__ qkw,
             ushort* __restrict__ vTw)
{
  __shared__ __align__(16) ushort smem[36864];   // 72 KB
  constexpr int NT = 9;
  const int wg = blockIdx.x;
  const int X = wg & 7, j = wg >> 3;
  const int bmT = X * 16 + j / NT;               // 128 M-tiles, 16 per XCD
  const int by = j - (j / NT) * NT;
  const int bm = bmT * 256, bn = by * 128;
  const int tid = threadIdx.x;
  const int lane = tid & 63, w = tid >> 6;
  const int wr = w >> 1, wc = w & 1;
  const int g = lane >> 4, l15 = lane & 15;

  f32x4 acc[4][4] = {};

  auto stage = [&](int buf, int k0) {            // 3 gload_lds per thread
    #pragma unroll
    for (int i = 0; i < 2; ++i) {                // A: 1024 slots (256 rows x 32)
      int s = i * 512 + tid;
      int row = s >> 2, cS = s & 3;
      int c = cS ^ ((row >> 1) & 3);
      gload_lds16(A + (size_t)(bm + row) * C_ + k0 + c * 8, &smem[buf * 8192 + s * 8]);
    }
    {                                            // B: 512 slots (128 rows x 32)
      int s = tid;
      int row = s >> 2, cS = s & 3;
      int c = cS ^ ((row >> 1) & 3);
      gload_lds16(Bt + (size_t)(bn + row) * C_ + k0 + c * 8, &smem[24576 + buf * 4096 + s * 8]);
    }
  };

  stage(0, 0);
  stage(1, 32);
  SCHED_FENCE();
  asm volatile("s_waitcnt vmcnt(3)" ::: "memory");   // stage(0) retired
  __builtin_amdgcn_s_barrier();
  SCHED_FENCE();

  #pragma unroll
  for (int t = 0; t < 12; ++t) {
    const int cur = t % 3;
    if (t < 10) stage((t + 2) % 3, (t + 2) * 32);

    bf16x8 af[4], bfr[4];
    #pragma unroll
    for (int m = 0; m < 4; ++m) {
      int row = wr * 64 + m * 16 + l15;          // 0..255
      int c = g ^ ((row >> 1) & 3);
      af[m] = *(const bf16x8*)&smem[cur * 8192 + row * 32 + c * 8];
    }
    #pragma unroll
    for (int n = 0; n < 4; ++n) {
      int row = wc * 64 + n * 16 + l15;          // 0..127
      int c = g ^ ((row >> 1) & 3);
      bfr[n] = *(const bf16x8*)&smem[24576 + cur * 4096 + row * 32 + c * 8];
    }
    #pragma unroll
    for (int m = 0; m < 4; ++m)
      #pragma unroll
      for (int n = 0; n < 4; ++n)
        acc[m][n] = MFMA16(af[m], bfr[n], acc[m][n]);

    if (t < 11) {
      SCHED_FENCE();                              // pin reads/MFMA above barrier
      if (t < 10) asm volatile("s_waitcnt vmcnt(3)" ::: "memory");  // stage(t+1) retired
      else        asm volatile("s_waitcnt vmcnt(0)" ::: "memory");  // last buf ready
      __builtin_amdgcn_s_barrier();
      SCHED_FENCE();                              // pin next stage/reads below
    }
  }

  if (by < 6) {
    // qk: LDS-staged swizzled store, 256x128 tile, full-line writes
    __syncthreads();                      // smem reuse safe (full fence)
    #pragma unroll
    for (int m = 0; m < 4; ++m)
      #pragma unroll
      for (int n = 0; n < 4; ++n) {
        int colL = wc * 64 + n * 16 + l15;
        float bv = bias[bn + colL];
        #pragma unroll
        for (int r = 0; r < 4; ++r) {
          int rowL = wr * 64 + m * 16 + g * 4 + r;     // 0..255
          smem[rowL * 128 + (colL ^ ((rowL & 7) << 3))] = f2bf(acc[m][n][r] + bv);
        }
      }
    __syncthreads();
    #pragma unroll
    for (int i = 0; i < 8; ++i) {
      int rowL = (tid >> 2) + (i >> 2) * 128;   // 0..255
      int slot = (i & 3) * 4 + (tid & 3);       // 0..15
      int c = slot * 8;
      bf16x8 vv = *(const bf16x8*)&smem[rowL * 128 + (c ^ ((rowL & 7) << 3))];
      *(bf16x8*)(qkw + (size_t)(bm + rowL) * QKS_ + bn + c) = vv;
    }
  } else {
    // v: LDS transpose staging (stride 272 = 17x16B -> aligned), full-row stores
    ushort (*CsT)[272] = (ushort(*)[272])smem;  // 128 x 272 = 34816 <= 36864
    __syncthreads();                      // smem reuse safe (full fence)
    #pragma unroll
    for (int m = 0; m < 4; ++m)
      #pragma unroll
      for (int n = 0; n < 4; ++n) {
        int colL = wc * 64 + n * 16 + l15;
        float bv = bias[bn + colL];
        int row0 = wr * 64 + m * 16 + g * 4;    // 0..255 (keys)
        uint lo = (uint)f2bf(acc[m][n][0] + bv) | ((uint)f2bf(acc[m][n][1] + bv) << 16);
        uint hi = (uint)f2bf(acc[m][n][2] + bv) | ((uint)f2bf(acc[m][n][3] + bv) << 16);
        uint2 uu; uu.x = lo; uu.y = hi;
        *(uint2*)&CsT[colL][row0] = uu;
      }
    __syncthreads();
    #pragma unroll
    for (int i = 0; i < 8; ++i) {
      int s = i * 512 + tid;                    // 4096 slots
      int colL = s >> 5;                        // 0..127
      int kc = s & 31;                          // 16B chunk along 256 keys
      int ch = (bn - 768) + colL;
      int hh = ch >> 6, dd = ch & 63;
      bf16x8 vv = *(const bf16x8*)&CsT[colL][kc * 8];
      *(bf16x8*)(vTw + ((size_t)(bmT * H_ + hh) * 64 + dd) * 256 + kc * 8) = vv;
    }
  }
}

// ---------------------------------------------------------------------------
// GEMM1 (proj) — R13/R16 verbatim: 128x128 tile, 256 threads, 3-buffer
// single-barrier K-loop with fences, vmcnt(4) counted, direct f32 stores.
// ---------------------------------------------------------------------------
__global__ __launch_bounds__(256, 3)
void k_gemm1(const ushort* __restrict__ A, const ushort* __restrict__ Bt,
             const float* __restrict__ bias, float* __restrict__ outf)
{
  __shared__ __align__(16) ushort smem[24576];   // A: 3x4096 | B: 3x4096
  constexpr int NT = 3;
  const int wg = blockIdx.x;
  const int X = wg & 7, j = wg >> 3;
  const int bmT = X * 32 + j / NT;
  const int by = j - (j / NT) * NT;
  const int bm = bmT * 128, bn = by * 128;
  const int tid = threadIdx.x;
  const int lane = tid & 63, w = tid >> 6;
  const int wr = w >> 1, wc = w & 1;
  const int g = lane >> 4, l15 = lane & 15;

  f32x4 acc[4][4] = {};

  auto stage = [&](int buf, int k0) {           // 4 gload_lds per thread
    #pragma unroll
    for (int i = 0; i < 2; ++i) {
      int s = i * 256 + tid;
      int row = s >> 2, cS = s & 3;
      int c = cS ^ ((row >> 1) & 3);
      gload_lds16(A  + (size_t)(bm + row) * C_ + k0 + c * 8, &smem[buf * 4096 + s * 8]);
      gload_lds16(Bt + (size_t)(bn + row) * C_ + k0 + c * 8, &smem[12288 + buf * 4096 + s * 8]);
    }
  };

  stage(0, 0);
  stage(1, 32);
  SCHED_FENCE();
  asm volatile("s_waitcnt vmcnt(4)" ::: "memory");
  __builtin_amdgcn_s_barrier();
  SCHED_FENCE();

  #pragma unroll
  for (int t = 0; t < 12; ++t) {
    const int cur = t % 3;
    if (t < 10) stage((t + 2) % 3, (t + 2) * 32);

    bf16x8 af[4], bfr[4];
    #pragma unroll
    for (int m = 0; m < 4; ++m) {
      int row = wr * 64 + m * 16 + l15;
      int c = g ^ ((row >> 1) & 3);
      af[m] = *(const bf16x8*)&smem[cur * 4096 + row * 32 + c * 8];
    }
    #pragma unroll
    for (int n = 0; n < 4; ++n) {
      int row = wc * 64 + n * 16 + l15;
      int c = g ^ ((row >> 1) & 3);
      bfr[n] = *(const bf16x8*)&smem[12288 + cur * 4096 + row * 32 + c * 8];
    }
    #pragma unroll
    for (int m = 0; m < 4; ++m)
      #pragma unroll
      for (int n = 0; n < 4; ++n)
        acc[m][n] = MFMA16(af[m], bfr[n], acc[m][n]);

    if (t < 11) {
      SCHED_FENCE();
      if (t < 10) asm volatile("s_waitcnt vmcnt(4)" ::: "memory");
      else        asm volatile("s_waitcnt vmcnt(0)" ::: "memory");
      __builtin_amdgcn_s_barrier();
      SCHED_FENCE();
    }
  }

  #pragma unroll
  for (int m = 0; m < 4; ++m)
    #pragma unroll
    for (int n = 0; n < 4; ++n) {
      int col = bn + wc * 64 + n * 16 + l15;
      float bv = bias[col];
      #pragma unroll
      for (int r = 0; r < 4; ++r) {
        int row = bm + wr * 64 + m * 16 + g * 4 + r;
        outf[(size_t)row * C_ + col] = acc[m][n][r] + bv;
      }
    }
}

// ---------------------------------------------------------------------------
// Attention — R16 verbatim dataflow (V loads as plain early arrays, NO
// prefetch rotation — R17's reg-rotation spilled to scratch, rule #20),
// with ONLY T5 setprio kept around the two MFMA clusters (scalar instr,
// zero register pressure; +4-7% in this barrier-free multi-wave regime).
// ---------------------------------------------------------------------------
__global__ __launch_bounds__(512, 4)
void k_attn(const ushort* __restrict__ qkw, const ushort* __restrict__ vTw,
            const ushort* __restrict__ membf, const ushort* __restrict__ memT,
            const float* __restrict__ gate, ushort* __restrict__ y)
{
  __shared__ ushort Ks[2][384][32];   // mem(0..127)+self(128..383) K, col-XOR swizzled
  __shared__ ushort Pb[8][32 * 32];   // per-wave P tile, sigma-swizzled

  const int b = blockIdx.x, h = blockIdx.y;
  const int tid = threadIdx.x, lane = tid & 63, w = tid >> 6;
  const int g = lane >> 4, l15 = lane & 15;
  const int q0 = w * 32;

  const ushort* qbase = qkw + (size_t)b * T_ * QKS_ + h * 64;
  const ushort* kcols = qbase + C_;                       // self-k columns
  const ushort* vbase = vTw + (size_t)(b * H_ + h) * 64 * 256;
  const ushort* mTb   = memT + (size_t)h * 64 * 128;
  const ushort* mKb   = membf + h * 64;

  // ---- stage Ks: 3072 16B slots over 512 threads ----
  #pragma unroll
  for (int i = 0; i < 6; ++i) {
    int s = i * 512 + tid;
    int kk = s / 1536, r4 = s - kk * 1536;
    int row = r4 >> 2, cS = r4 & 3;
    int c = cS ^ ((row >> 1) & 3);                        // inverse swizzle on source
    const ushort* src = (row < M_)
        ? mKb + (size_t)row * C_ + kk * 32 + c * 8
        : kcols + (size_t)(row - M_) * QKS_ + kk * 32 + c * 8;
    gload_lds16(src, &Ks[0][0][0] + s * 8);
  }

  // ---- Q fragments ----
  bf16x8 qf[2][2];
  #pragma unroll
  for (int m = 0; m < 2; ++m)
    #pragma unroll
    for (int kk = 0; kk < 2; ++kk)
      qf[m][kk] = *(const bf16x8*)(qbase + (size_t)(q0 + m * 16 + l15) * QKS_ + kk * 32 + g * 8);

  __syncthreads();   // drains global_load_lds (full fence)

  f32x4 yacc[2][4] = {};
  float rsum[2][4] = {};
  ushort* P = &Pb[w][0];

  const int c0 = (q0 >= WIN_) ? ((q0 - WIN_) >> 5) : 0;
  const int nch_self = (q0 >> 5) - c0 + 1;
  const int ss = M_ + c0 * 32;

  for (int ch = 0; ch < 4 + nch_self; ++ch) {
    const bool is_mem = (ch < 4);
    const int r0 = is_mem ? ch * 32 : ss + (ch - 4) * 32;
    const ushort* vsrc = is_mem ? mTb : vbase;
    const int vld = is_mem ? 128 : 256;
    const int keyoff = is_mem ? r0 : (r0 - M_);

    // ---- QK^T: S[32 q][32 keys] ----
    f32x4 s_[2][2];
    #pragma unroll
    for (int m = 0; m < 2; ++m)
      #pragma unroll
      for (int n = 0; n < 2; ++n)
        s_[m][n] = (f32x4){0.f, 0.f, 0.f, 0.f};
    __builtin_amdgcn_s_setprio(1);
    #pragma unroll
    for (int n = 0; n < 2; ++n) {
      int R = r0 + n * 16 + l15;
      int c = g ^ ((R >> 1) & 3);
      #pragma unroll
      for (int kk = 0; kk < 2; ++kk) {
        bf16x8 kf = *(const bf16x8*)&Ks[kk][R][c * 8];
        #pragma unroll
        for (int m = 0; m < 2; ++m)
          s_[m][n] = MFMA16(qf[m][kk], kf, s_[m][n]);
      }
    }
    __builtin_amdgcn_s_setprio(0);

    // ---- issue V loads early (hide global latency under exp/pack) ----
    bf16x8 vb[4];
    #pragma unroll
    for (int n = 0; n < 4; ++n) {
      int dd = n * 16 + l15;
      vb[n] = *(const bf16x8*)(vsrc + (size_t)dd * vld + keyoff + g * 8);
    }

    // ---- mask + exp + P write ----
    #pragma unroll
    for (int m = 0; m < 2; ++m)
      #pragma unroll
      for (int n = 0; n < 2; ++n) {
        int key_row = r0 + n * 16 + l15;
        int jj = key_row - M_;
        int kc = n * 16 + l15;
        float p[4];
        #pragma unroll
        for (int r = 0; r < 4; ++r) {
          int qi = q0 + m * 16 + g * 4 + r;
          bool ok = is_mem || ((jj <= qi) && (qi - jj <= WIN_));
          float e = ok ? exp2f(s_[m][n][r] * 0.18033688011112042f) : 0.f;
          rsum[m][r] += e;
          p[r] = e;
        }
        uint u01 = cvtpk(p[0], p[1]);
        uint u23 = cvtpk(p[2], p[3]);
        #pragma unroll
        for (int r = 0; r < 4; ++r) {
          int ql = m * 16 + g * 4 + r;
          int sig = ((ql >> 1) ^ (ql >> 2)) & 3;
          uint u = (r < 2) ? u01 : u23;
          ushort val = (r & 1) ? (ushort)(u >> 16) : (ushort)(u & 0xffffu);
          P[ql * 32 + (kc ^ (sig << 3))] = val;
        }
      }

    // ---- PV: yacc += P[32x32] * V[32 keys x 64 d] ----
    bf16x8 pa[2];
    #pragma unroll
    for (int m = 0; m < 2; ++m) {
      int row = m * 16 + l15;
      int sig = ((row >> 1) ^ (row >> 2)) & 3;
      pa[m] = *(const bf16x8*)&P[row * 32 + ((g ^ sig) << 3)];
    }
    __builtin_amdgcn_s_setprio(1);
    #pragma unroll
    for (int n = 0; n < 4; ++n)
      #pragma unroll
      for (int m = 0; m < 2; ++m)
        yacc[m][n] = MFMA16(pa[m], vb[n], yacc[m][n]);
    __builtin_amdgcn_s_setprio(0);
  }

  // ---- row-sum reduce across the 16 lanes sharing each q row ----
  float inv[2][4];
  #pragma unroll
  for (int m = 0; m < 2; ++m)
    #pragma unroll
    for (int r = 0; r < 4; ++r) {
      float v = rsum[m][r];
      v += __shfl_xor(v, 1); v += __shfl_xor(v, 2);
      v += __shfl_xor(v, 4); v += __shfl_xor(v, 8);
      inv[m][r] = 1.f / v;
    }

  // ---- epilogue: y = (P V / l) * gate, bf16 ----
  #pragma unroll
  for (int m = 0; m < 2; ++m)
    #pragma unroll
    for (int n = 0; n < 4; ++n) {
      int dd = n * 16 + l15;
      float gv = gate[h * 64 + dd];
      #pragma unroll
      for (int r = 0; r < 4; ++r) {
        int qi = q0 + m * 16 + g * 4 + r;
        y[(size_t)(b * T_ + qi) * C_ + h * 64 + dd] = f2bf(yacc[m][n][r] * inv[m][r] * gv);
      }
    }
}

// ---------------------------------------------------------------------------
extern "C" void kernel_launch(void* const* d_in, const int* in_sizes, int n_in,
                              void* d_out, int out_size, void* d_ws, size_t ws_size,
                              hipStream_t stream) {
  const float* x      = (const float*)d_in[0];
  const float* memory = (const float*)d_in[1];
  const float* W_qkv  = (const float*)d_in[2];
  const float* b_qkv  = (const float*)d_in[3];
  const float* W_proj = (const float*)d_in[4];
  const float* b_proj = (const float*)d_in[5];
  const float* gate   = (const float*)d_in[6];
  float* out = (float*)d_out;

  ushort* p = (ushort*)d_ws;
  ushort* Wq_t  = p;  p += (size_t)C_ * C3_;          //   442368
  ushort* Wp_t  = p;  p += (size_t)C_ * C_;           //   147456
  ushort* membf = p;  p += (size_t)M_ * C_;           //    49152
  ushort* memT  = p;  p += (size_t)NMT_;              //    49152
  ushort* qkw   = p;  p += (size_t)B_ * T_ * QKS_;    // 25165824
  ushort* vTw   = p;  p += (size_t)B_ * T_ * C_;      // 12582912
  ushort* xybf  = p;  p += (size_t)B_ * T_ * C_;      // 12582912 (x_bf, then y)

  dim3 blk(256);

  int prep_items = NX4_ + NM4_ + NMT_ + NWQ_ + NWP_;
  k_prep<<<dim3((prep_items + 255) / 256), blk, 0, stream>>>(
      x, memory, W_qkv, W_proj, xybf, membf, memT, Wq_t, Wp_t);

  k_gemm0<<<dim3(1152), dim3(512), 0, stream>>>(xybf, Wq_t, b_qkv, qkw, vTw);

  k_attn<<<dim3(B_, H_), dim3(512), 0, stream>>>(qkw, vTw, membf, memT, gate, xybf);

  k_gemm1<<<dim3(768), blk, 0, stream>>>(xybf, Wp_t, b_proj, out);
}